// Round 5
// baseline (10093.109 us; speedup 1.0000x reference)
//
#include <hip/hip_runtime.h>
#include <hip/hip_bf16.h>

typedef __bf16 bf16;
typedef __bf16 bf16x8 __attribute__((ext_vector_type(8)));
typedef __bf16 bf16x4 __attribute__((ext_vector_type(4)));
typedef float floatx4 __attribute__((ext_vector_type(4)));

#define MFMA16(a, b, c) __builtin_amdgcn_mfma_f32_16x16x32_bf16((a), (b), (c), 0, 0, 0)

static constexpr int Bd = 64, Ld = 128, Ed = 512, Nd = 512, Hd = 1024;
static constexpr int NBLK = 256;
static constexpr float LOG2E = 1.4426950408889634f;
static constexpr float TWO_LOG2E = 2.8853900817779268f;
static constexpr unsigned long long WDOG_TICKS = 1000000ull;  // ~10ms @100MHz RTC: hang -> wrong-answer, not container kill

__device__ __forceinline__ float fexp2(float x) { return __builtin_amdgcn_exp2f(x); }
__device__ __forceinline__ float frcp(float x) { return __builtin_amdgcn_rcpf(x); }
__device__ __forceinline__ float sigmoid_f(float x) { return frcp(1.0f + fexp2(-x * LOG2E)); }
__device__ __forceinline__ float tanh_f(float x) { return 1.0f - 2.0f * frcp(fexp2(x * TWO_LOG2E) + 1.0f); }

__device__ __forceinline__ bf16x8 cvt8(const float* p) {
    float4 f0 = *(const float4*)p;
    float4 f1 = *(const float4*)(p + 4);
    bf16x8 r = {(bf16)f0.x, (bf16)f0.y, (bf16)f0.z, (bf16)f0.w,
                (bf16)f1.x, (bf16)f1.y, (bf16)f1.z, (bf16)f1.w};
    return r;
}

// ---------------- coherent-point (Infinity Cache) access helpers: no cache maintenance needed ----------------
#define AS_RLX __ATOMIC_RELAXED
#define SC_AGT __HIP_MEMORY_SCOPE_AGENT

__device__ __forceinline__ float ldf_cg(const float* p) { return __hip_atomic_load(p, AS_RLX, SC_AGT); }
__device__ __forceinline__ void stf_cg(float* p, float v) { __hip_atomic_store(p, v, AS_RLX, SC_AGT); }
__device__ __forceinline__ void sth_cg(bf16* p, bf16 v) {
    __hip_atomic_store((unsigned short*)p, __builtin_bit_cast(unsigned short, v), AS_RLX, SC_AGT);
}
__device__ __forceinline__ float2 ldf2_cg(const float* p) {
    unsigned long long u = __hip_atomic_load((const unsigned long long*)p, AS_RLX, SC_AGT);
    return __builtin_bit_cast(float2, u);
}
__device__ __forceinline__ bf16x8 ldh8_cg(const bf16* p) {
    const unsigned long long* q = (const unsigned long long*)p;
    unsigned long long a = __hip_atomic_load(q, AS_RLX, SC_AGT);
    unsigned long long b = __hip_atomic_load(q + 1, AS_RLX, SC_AGT);
    union { unsigned long long u[2]; bf16x8 v; } c;
    c.u[0] = a; c.u[1] = b;
    return c.v;
}
__device__ __forceinline__ bf16x8 cvt8_cg(const float* p) {
    float2 a = ldf2_cg(p), b = ldf2_cg(p + 2), c = ldf2_cg(p + 4), d = ldf2_cg(p + 6);
    bf16x8 r = {(bf16)a.x, (bf16)a.y, (bf16)b.x, (bf16)b.y,
                (bf16)c.x, (bf16)c.y, (bf16)d.x, (bf16)d.y};
    return r;
}

// ---------------------------------------------------------------- f32 -> bf16 bulk convert (n % 8 == 0)
__global__ __launch_bounds__(256) void k_conv(const float* __restrict__ src, bf16* __restrict__ dst, int n) {
    int i0 = (blockIdx.x * 256 + threadIdx.x) * 8;
    if (i0 >= n) return;
    *(bf16x8*)(dst + i0) = cvt8(src + i0);
}

// ---------------------------------------------------------------- init: hb_bf16 = (bf16)state, hb_f32 = state
__global__ __launch_bounds__(256) void k_init(const float* __restrict__ state, bf16* __restrict__ hb,
                                              float* __restrict__ hb32) {
    int i0 = (blockIdx.x * 256 + threadIdx.x) * 8;
    *(bf16x8*)(hb + i0) = cvt8(state + i0);
    *(float4*)(hb32 + i0) = *(const float4*)(state + i0);
    *(float4*)(hb32 + i0 + 4) = *(const float4*)(state + i0 + 4);
}

// ---------------------------------------------------------------- keys_c = (value @ Wk^T) * 2log2e  [bf16]
__global__ __launch_bounds__(256) void k_keys(const bf16* __restrict__ val, const bf16* __restrict__ Wk,
                                              bf16* __restrict__ keys_c) {
    const int lane = threadIdx.x & 63, wave = threadIdx.x >> 6;
    const int l16 = lane & 15, q8 = (lane >> 4) * 8;
    const int mblk = blockIdx.x >> 4, nblk = blockIdx.x & 15;
    const int m_base = mblk * 64 + (wave & 1) * 32;
    const int n_base = nblk * 64 + (wave >> 1) * 32;
    const bf16* a0p = val + (size_t)(m_base + l16) * 1024 + q8;
    const bf16* a1p = a0p + 16 * 1024;
    const bf16* b0p = Wk + (size_t)(n_base + l16) * 1024 + q8;
    const bf16* b1p = b0p + 16 * 1024;
    floatx4 acc[2][2] = {};
    for (int k0 = 0; k0 < 1024; k0 += 32) {
        bf16x8 a0 = *(const bf16x8*)(a0p + k0);
        bf16x8 a1 = *(const bf16x8*)(a1p + k0);
        bf16x8 b0 = *(const bf16x8*)(b0p + k0);
        bf16x8 b1 = *(const bf16x8*)(b1p + k0);
        acc[0][0] = MFMA16(a0, b0, acc[0][0]);
        acc[0][1] = MFMA16(a0, b1, acc[0][1]);
        acc[1][0] = MFMA16(a1, b0, acc[1][0]);
        acc[1][1] = MFMA16(a1, b1, acc[1][1]);
    }
    const int mr = (lane >> 4) * 4;
    for (int im = 0; im < 2; im++)
        for (int in = 0; in < 2; in++)
            for (int r = 0; r < 4; r++) {
                int m = m_base + im * 16 + mr + r;
                int n = n_base + in * 16 + l16;
                keys_c[(size_t)m * 1024 + n] = (bf16)(acc[im][in][r] * TWO_LOG2E);
            }
}

// ---------------------------------------------------------------- barrier state reset (graph-replay safe)
// bar[0..511]: 32 group counters at stride 16 uints; bar[512]: generation flag.
__global__ void k_reset(unsigned* bar) {
    for (int i = threadIdx.x; i < 513; i += blockDim.x)
        __hip_atomic_store(&bar[i], 0u, AS_RLX, SC_AGT);
}

// ---------------------------------------------------------------- tree grid barrier: no fences, no L2 impact
// Cross-block data moves only through coherent-point (agent-scope) accesses, so the barrier
// needs no cache invalidation — just store-ack ordering (s_waitcnt vmcnt(0)) + arrival counting.
// Watchdog: any stall > ~10ms breaks out (wrong results, clean termination).
__device__ __forceinline__ void gbar(unsigned* bar, unsigned gen) {
    asm volatile("s_waitcnt vmcnt(0)" ::: "memory");   // drain this wave's coherent stores
    __syncthreads();
    const int tid = threadIdx.x;
    if (blockIdx.x == 0) {
        if (tid < 64) {
            if (tid == 0)
                __hip_atomic_fetch_add(&bar[0], 1u, AS_RLX, SC_AGT);
            unsigned long long t0 = __builtin_amdgcn_s_memrealtime();
            for (;;) {   // lanes 0..31 poll the 32 group counters in parallel
                unsigned v = (tid < 32) ? __hip_atomic_load(&bar[tid * 16], AS_RLX, SC_AGT) : 0xFFFFFFFFu;
                if (__all((int)(v >= gen * 8u))) break;
                if (__builtin_amdgcn_s_memrealtime() - t0 > WDOG_TICKS) break;
                __builtin_amdgcn_s_sleep(2);
            }
            if (tid == 0) __hip_atomic_store(&bar[512], gen, AS_RLX, SC_AGT);
        }
    } else {
        if (tid == 0) {
            __hip_atomic_fetch_add(&bar[(blockIdx.x >> 3) * 16], 1u, AS_RLX, SC_AGT);
            unsigned long long t0 = __builtin_amdgcn_s_memrealtime();
            while (__hip_atomic_load(&bar[512], AS_RLX, SC_AGT) < gen) {
                if (__builtin_amdgcn_s_memrealtime() - t0 > WDOG_TICKS) break;
                __builtin_amdgcn_s_sleep(2);
            }
        }
    }
    __syncthreads();
}

// ---------------------------------------------------------------- persistent kernel: 128 steps x 5 phases
__global__ __launch_bounds__(256) void k_persist(
    const float* __restrict__ emb, const float* __restrict__ mask,
    const bf16* __restrict__ value_c, const bf16* __restrict__ keys_c,
    const bf16* __restrict__ Wih, const bf16* __restrict__ Whh,
    const float* __restrict__ bih, const float* __restrict__ bhh,
    const bf16* __restrict__ Wq, const bf16* __restrict__ Wm,
    const float* __restrict__ bm, const float* __restrict__ v_att,
    bf16* hb, float* hb32, bf16* rnn, float* qc,
    float* scores, float* context, float* out_f, unsigned* bar) {
    const int bid = blockIdx.x, tid = threadIdx.x;
    const int lane = tid & 63, w = tid >> 6;
    const int l16 = lane & 15, q8 = (lane >> 4) * 8, mr = (lane >> 4) * 4;
    __shared__ __align__(16) float lds[4096];

    // GEMM tile decomposition (XCD-swizzled: 4 mt-partners of one cs share bid%8)
    const int mt = (bid >> 3) & 3;
    const int cs = (bid & 7) | ((bid >> 5) << 3);
    const int b_row = mt * 16 + l16;
    const int jcol = cs * 16 + l16;

    const float biasR = bih[jcol] + bhh[jcol];
    const float biasZ = bih[1024 + jcol] + bhh[1024 + jcol];
    const float biasXN = bih[2048 + jcol];
    const float biasHN = bhh[2048 + jcol];
    const float biasM = bm[jcol];

    // P3 mapping: global wave -> (b, 32-n chunk)
    const int gw = bid * 4 + w;
    const int p3_b = gw >> 4;
    const int p3_n0 = (gw & 15) * 32;

    // P4 mapping
    const int b4 = bid >> 2, hc = bid & 3;

    // v_att resident in registers all 128 steps
    float vv[16];
    {
        float4 a0 = *(const float4*)(v_att + lane * 8);
        float4 a1 = *(const float4*)(v_att + lane * 8 + 4);
        float4 b0 = *(const float4*)(v_att + 512 + lane * 8);
        float4 b1 = *(const float4*)(v_att + 512 + lane * 8 + 4);
        vv[0] = a0.x; vv[1] = a0.y; vv[2] = a0.z; vv[3] = a0.w;
        vv[4] = a1.x; vv[5] = a1.y; vv[6] = a1.z; vv[7] = a1.w;
        vv[8] = b0.x; vv[9] = b0.y; vv[10] = b0.z; vv[11] = b0.w;
        vv[12] = b1.x; vv[13] = b1.y; vv[14] = b1.z; vv[15] = b1.w;
    }

    unsigned gen = 0;
    for (int step = 0; step < Ld; ++step) {
        // ================= P1: GRU gates -> rnn (4-way K-split across waves) =================
        {
            floatx4 aR = {}, aZ = {}, aXN = {}, aHN = {};
            {   // seg1: emb (normal cached loads), K=512, wave slice 128
                const float* ae = emb + ((size_t)b_row * Ld + step) * Ed + w * 128 + q8;
                const bf16* w0 = Wih + (size_t)jcol * 1536 + w * 128 + q8;
                const bf16* w1 = Wih + (size_t)(1024 + jcol) * 1536 + w * 128 + q8;
                const bf16* w2 = Wih + (size_t)(2048 + jcol) * 1536 + w * 128 + q8;
#pragma unroll
                for (int k = 0; k < 128; k += 32) {
                    bf16x8 a = cvt8(ae + k);
                    aR = MFMA16(a, *(const bf16x8*)(w0 + k), aR);
                    aZ = MFMA16(a, *(const bf16x8*)(w1 + k), aZ);
                    aXN = MFMA16(a, *(const bf16x8*)(w2 + k), aXN);
                }
            }
            {   // seg2: hb (coherent loads), K=1024, wave slice 256
                const bf16* ah = hb + (size_t)b_row * Hd + w * 256 + q8;
                const bf16* u0 = Wih + (size_t)jcol * 1536 + 512 + w * 256 + q8;
                const bf16* u1 = Wih + (size_t)(1024 + jcol) * 1536 + 512 + w * 256 + q8;
                const bf16* u2 = Wih + (size_t)(2048 + jcol) * 1536 + 512 + w * 256 + q8;
                const bf16* v0 = Whh + (size_t)jcol * 1024 + w * 256 + q8;
                const bf16* v1 = Whh + (size_t)(1024 + jcol) * 1024 + w * 256 + q8;
                const bf16* v2 = Whh + (size_t)(2048 + jcol) * 1024 + w * 256 + q8;
#pragma unroll 4
                for (int k = 0; k < 256; k += 32) {
                    bf16x8 a = ldh8_cg(ah + k);
                    aR = MFMA16(a, *(const bf16x8*)(u0 + k), aR);
                    aZ = MFMA16(a, *(const bf16x8*)(u1 + k), aZ);
                    aXN = MFMA16(a, *(const bf16x8*)(u2 + k), aXN);
                    aHN = MFMA16(a, *(const bf16x8*)(v2 + k), aHN);
                    aR = MFMA16(a, *(const bf16x8*)(v0 + k), aR);
                    aZ = MFMA16(a, *(const bf16x8*)(v1 + k), aZ);
                }
            }
            *(floatx4*)&lds[w * 1024 + 0 + lane * 4] = aR;
            *(floatx4*)&lds[w * 1024 + 256 + lane * 4] = aZ;
            *(floatx4*)&lds[w * 1024 + 512 + lane * 4] = aXN;
            *(floatx4*)&lds[w * 1024 + 768 + lane * 4] = aHN;
            __syncthreads();
            if (tid < 64) {
                floatx4 R = {}, Z = {}, XN = {}, HN = {};
#pragma unroll
                for (int ww = 0; ww < 4; ++ww) {
                    R += *(floatx4*)&lds[ww * 1024 + 0 + lane * 4];
                    Z += *(floatx4*)&lds[ww * 1024 + 256 + lane * 4];
                    XN += *(floatx4*)&lds[ww * 1024 + 512 + lane * 4];
                    HN += *(floatx4*)&lds[ww * 1024 + 768 + lane * 4];
                }
#pragma unroll
                for (int r = 0; r < 4; ++r) {
                    int b = mt * 16 + mr + r;
                    float rg = sigmoid_f(R[r] + biasR);
                    float zg = sigmoid_f(Z[r] + biasZ);
                    float ng = tanh_f(XN[r] + biasXN + rg * (HN[r] + biasHN));
                    float hp = ldf_cg(&hb32[(size_t)b * Hd + jcol]);
                    sth_cg(&rnn[(size_t)b * Hd + jcol], (bf16)((1.0f - zg) * ng + zg * hp));
                }
            }
        }
        gbar(bar, ++gen);

        // ================= P2: q = (rnn @ Wq^T) * 2log2e =================
        {
            const bf16* ap = rnn + (size_t)b_row * Hd + w * 256 + q8;
            const bf16* bp = Wq + (size_t)jcol * Hd + w * 256 + q8;
            floatx4 acc = {};
#pragma unroll 4
            for (int k = 0; k < 256; k += 32)
                acc = MFMA16(ldh8_cg(ap + k), *(const bf16x8*)(bp + k), acc);
            *(floatx4*)&lds[w * 256 + lane * 4] = acc;
            __syncthreads();
            if (tid < 64) {
                floatx4 s = *(floatx4*)&lds[lane * 4] + *(floatx4*)&lds[256 + lane * 4] +
                            *(floatx4*)&lds[512 + lane * 4] + *(floatx4*)&lds[768 + lane * 4];
#pragma unroll
                for (int r = 0; r < 4; ++r)
                    stf_cg(&qc[(size_t)(mt * 16 + mr + r) * Hd + jcol], s[r] * TWO_LOG2E);
            }
        }
        gbar(bar, ++gen);

        // ================= P3: scores[b,n] = sum_h v * tanh(q + k) =================
        {
            const float* qp = qc + (size_t)p3_b * Hd;
            float qv[16];
            {
                float2 a0 = ldf2_cg(qp + lane * 8), a1 = ldf2_cg(qp + lane * 8 + 2);
                float2 a2 = ldf2_cg(qp + lane * 8 + 4), a3 = ldf2_cg(qp + lane * 8 + 6);
                float2 b0 = ldf2_cg(qp + 512 + lane * 8), b1 = ldf2_cg(qp + 512 + lane * 8 + 2);
                float2 b2 = ldf2_cg(qp + 512 + lane * 8 + 4), b3 = ldf2_cg(qp + 512 + lane * 8 + 6);
                qv[0] = a0.x; qv[1] = a0.y; qv[2] = a1.x; qv[3] = a1.y;
                qv[4] = a2.x; qv[5] = a2.y; qv[6] = a3.x; qv[7] = a3.y;
                qv[8] = b0.x; qv[9] = b0.y; qv[10] = b1.x; qv[11] = b1.y;
                qv[12] = b2.x; qv[13] = b2.y; qv[14] = b3.x; qv[15] = b3.y;
            }
            const bf16* kbase = keys_c + ((size_t)p3_b * Nd + p3_n0) * Hd + lane * 8;
#pragma unroll 2
            for (int i = 0; i < 32; ++i) {
                const bf16* kp = kbase + (size_t)i * Hd;
                bf16x8 k0 = *(const bf16x8*)kp;
                bf16x8 k1 = *(const bf16x8*)(kp + 512);
                float acc = 0.f;
#pragma unroll
                for (int jj = 0; jj < 8; ++jj) {
                    float x = qv[jj] + (float)k0[jj];
                    float tv = __builtin_fmaf(-2.0f, frcp(fexp2(x) + 1.0f), 1.0f);
                    acc = __builtin_fmaf(vv[jj], tv, acc);
                }
#pragma unroll
                for (int jj = 0; jj < 8; ++jj) {
                    float x = qv[8 + jj] + (float)k1[jj];
                    float tv = __builtin_fmaf(-2.0f, frcp(fexp2(x) + 1.0f), 1.0f);
                    acc = __builtin_fmaf(vv[8 + jj], tv, acc);
                }
#pragma unroll
                for (int off = 32; off; off >>= 1) acc += __shfl_down(acc, off, 64);
                if (lane == 0) stf_cg(&scores[(size_t)p3_b * Nd + p3_n0 + i], acc);
            }
        }
        gbar(bar, ++gen);

        // ================= P4: softmax + context (atomic-free) =================
        {
            float* sm = lds;
            float* red = lds + 512;
            float* part = lds + 768;
            float s0 = ldf_cg(&scores[(size_t)b4 * Nd + tid]);
            float s1 = ldf_cg(&scores[(size_t)b4 * Nd + 256 + tid]);
            if (!(mask[(size_t)b4 * Nd + tid] > 0.f)) s0 = -1e9f;
            if (!(mask[(size_t)b4 * Nd + 256 + tid] > 0.f)) s1 = -1e9f;
            float m = fmaxf(s0, s1);
#pragma unroll
            for (int off = 32; off; off >>= 1) m = fmaxf(m, __shfl_xor(m, off, 64));
            if (lane == 0) red[w] = m;
            __syncthreads();
            float mx = fmaxf(fmaxf(red[0], red[1]), fmaxf(red[2], red[3]));
            float p0 = fexp2((s0 - mx) * LOG2E);
            float p1 = fexp2((s1 - mx) * LOG2E);
            float ss = p0 + p1;
#pragma unroll
            for (int off = 32; off; off >>= 1) ss += __shfl_xor(ss, off, 64);
            if (lane == 0) red[4 + w] = ss;
            __syncthreads();
            float inv = frcp(red[4] + red[5] + red[6] + red[7]);
            sm[tid] = p0 * inv;
            sm[256 + tid] = p1 * inv;
            __syncthreads();
            if (hc == 0) {   // attns output: host-read after kernel end -> normal stores
                float* ao = out_f + (size_t)Bd * Ld * Hd + ((size_t)b4 * Ld + step) * Nd;
                ao[tid] = sm[tid];
                ao[256 + tid] = sm[256 + tid];
            }
            const int h0 = hc * 256 + lane * 4;
            const bf16* vb = value_c + ((size_t)b4 * Nd + w * 128) * Hd + h0;
            float c0 = 0.f, c1 = 0.f, c2 = 0.f, c3 = 0.f;
#pragma unroll 4
            for (int n = 0; n < 128; ++n) {
                float a = sm[w * 128 + n];
                bf16x4 vt = *(const bf16x4*)(vb + (size_t)n * Hd);
                c0 = __builtin_fmaf(a, (float)vt[0], c0);
                c1 = __builtin_fmaf(a, (float)vt[1], c1);
                c2 = __builtin_fmaf(a, (float)vt[2], c2);
                c3 = __builtin_fmaf(a, (float)vt[3], c3);
            }
            *(floatx4*)&part[w * 256 + lane * 4] = (floatx4){c0, c1, c2, c3};
            __syncthreads();
            stf_cg(&context[(size_t)b4 * Hd + hc * 256 + tid],
                   part[tid] + part[256 + tid] + part[512 + tid] + part[768 + tid]);
        }
        gbar(bar, ++gen);

        // ================= P5: new_state = tanh([rnn|ctx] @ Wm^T + bm) =================
        {
            const bf16* Bp = Wm + (size_t)jcol * 2048 + q8;
            floatx4 acc = {};
            if (w < 2) {
                const bf16* ar = rnn + (size_t)b_row * Hd + w * 512 + q8;
                const bf16* bp = Bp + w * 512;
#pragma unroll 4
                for (int k = 0; k < 512; k += 32)
                    acc = MFMA16(ldh8_cg(ar + k), *(const bf16x8*)(bp + k), acc);
            } else {
                const float* ac = context + (size_t)b_row * Hd + (w - 2) * 512 + q8;
                const bf16* bp = Bp + 1024 + (w - 2) * 512;
#pragma unroll 4
                for (int k = 0; k < 512; k += 32)
                    acc = MFMA16(cvt8_cg(ac + k), *(const bf16x8*)(bp + k), acc);
            }
            *(floatx4*)&lds[w * 256 + lane * 4] = acc;
            __syncthreads();
            if (tid < 64) {
                floatx4 s = *(floatx4*)&lds[lane * 4] + *(floatx4*)&lds[256 + lane * 4] +
                            *(floatx4*)&lds[512 + lane * 4] + *(floatx4*)&lds[768 + lane * 4];
#pragma unroll
                for (int r = 0; r < 4; ++r) {
                    int b = mt * 16 + mr + r;
                    float h = tanh_f(s[r] + biasM);
                    out_f[((size_t)b * Ld + step) * Hd + jcol] = h;   // host-read: normal store
                    sth_cg(&hb[(size_t)b * Hd + jcol], (bf16)h);
                    stf_cg(&hb32[(size_t)b * Hd + jcol], h);
                }
            }
        }
        gbar(bar, ++gen);
    }
}

extern "C" void kernel_launch(void* const* d_in, const int* in_sizes, int n_in,
                              void* d_out, int out_size, void* d_ws, size_t ws_size,
                              hipStream_t stream) {
    const float* emb = (const float*)d_in[0];
    const float* value = (const float*)d_in[1];
    const float* mask = (const float*)d_in[2];
    const float* state = (const float*)d_in[3];
    const float* Wih = (const float*)d_in[4];
    const float* bih = (const float*)d_in[5];
    const float* Whh = (const float*)d_in[6];
    const float* bhh = (const float*)d_in[7];
    const float* Wq = (const float*)d_in[8];
    const float* Wk = (const float*)d_in[9];
    const float* v_att = (const float*)d_in[10];
    const float* Wm = (const float*)d_in[11];
    const float* bm = (const float*)d_in[12];

    char* ws = (char*)d_ws;
    bf16* hb = (bf16*)(ws);                   //     131,072
    float* hb32 = (float*)(ws + 131072);      //     262,144
    bf16* rnn = (bf16*)(ws + 393216);         //     131,072
    float* qc = (float*)(ws + 524288);        //     262,144
    float* scores = (float*)(ws + 786432);    //     131,072
    float* context = (float*)(ws + 917504);   //     262,144
    bf16* value_c = (bf16*)(ws + 1179648);    //  67,108,864
    bf16* Wih_c = (bf16*)(ws + 68288512);     //   9,437,184
    bf16* Whh_c = (bf16*)(ws + 77725696);     //   6,291,456
    bf16* Wq_c = (bf16*)(ws + 84017152);      //   2,097,152
    bf16* Wk_c = (bf16*)(ws + 86114304);      //   2,097,152
    bf16* Wm_c = (bf16*)(ws + 88211456);      //   4,194,304
    bf16* keys_c = (bf16*)(ws + 92405760);    //  67,108,864
    unsigned* bar = (unsigned*)(ws + 159514624);  // 513 uints: 32 padded counters + flag

    float* out_f = (float*)d_out;

    k_conv<<<16384, 256, 0, stream>>>(value, value_c, 33554432);
    k_conv<<<2304, 256, 0, stream>>>(Wih, Wih_c, 4718592);
    k_conv<<<1536, 256, 0, stream>>>(Whh, Whh_c, 3145728);
    k_conv<<<512, 256, 0, stream>>>(Wq, Wq_c, 1048576);
    k_conv<<<512, 256, 0, stream>>>(Wk, Wk_c, 1048576);
    k_conv<<<1024, 256, 0, stream>>>(Wm, Wm_c, 2097152);
    k_init<<<32, 256, 0, stream>>>(state, hb, hb32);
    k_keys<<<8192, 256, 0, stream>>>(value_c, Wk_c, keys_c);
    k_reset<<<1, 256, 0, stream>>>(bar);

    // Plain launch (graph-capture-proven). 256 blocks x 4 waves x 16KB LDS x <=136 VGPR
    // on 256 CUs -> co-residency guaranteed by capacity; watchdog converts any
    // pathological stall into a terminating (wrong-answer) run instead of a hang.
    k_persist<<<NBLK, 256, 0, stream>>>(emb, mask, value_c, keys_c, Wih_c, Whh_c, bih, bhh,
                                        Wq_c, Wm_c, bm, v_att, hb, hb32, rnn, qc,
                                        scores, context, out_f, bar);
}

// Round 6
// 8574.820 us; speedup vs baseline: 1.1771x; 1.1771x over previous
//
#include <hip/hip_runtime.h>
#include <hip/hip_bf16.h>

typedef __bf16 bf16;
typedef __bf16 bf16x8 __attribute__((ext_vector_type(8)));
typedef __bf16 bf16x4 __attribute__((ext_vector_type(4)));
typedef float floatx4 __attribute__((ext_vector_type(4)));

#define MFMA16(a, b, c) __builtin_amdgcn_mfma_f32_16x16x32_bf16((a), (b), (c), 0, 0, 0)

static constexpr int Bd = 64, Ld = 128, Ed = 512, Nd = 512, Hd = 1024;
static constexpr int NBLK = 512;           // 2 blocks/CU exactly -> co-residency by capacity
static constexpr float LOG2E = 1.4426950408889634f;
static constexpr float TWO_LOG2E = 2.8853900817779268f;
static constexpr unsigned long long WDOG_TICKS = 1000000ull;  // ~10ms: hang -> wrong answer, not container kill

__device__ __forceinline__ float fexp2(float x) { return __builtin_amdgcn_exp2f(x); }
__device__ __forceinline__ float frcp(float x) { return __builtin_amdgcn_rcpf(x); }
__device__ __forceinline__ float sigmoid_f(float x) { return frcp(1.0f + fexp2(-x * LOG2E)); }
__device__ __forceinline__ float tanh_f(float x) { return 1.0f - 2.0f * frcp(fexp2(x * TWO_LOG2E) + 1.0f); }

__device__ __forceinline__ bf16x8 cvt8(const float* p) {
    float4 f0 = *(const float4*)p;
    float4 f1 = *(const float4*)(p + 4);
    bf16x8 r = {(bf16)f0.x, (bf16)f0.y, (bf16)f0.z, (bf16)f0.w,
                (bf16)f1.x, (bf16)f1.y, (bf16)f1.z, (bf16)f1.w};
    return r;
}

// ---------------- coherent-point (Infinity Cache) access helpers: no cache maintenance needed ----------------
#define AS_RLX __ATOMIC_RELAXED
#define SC_AGT __HIP_MEMORY_SCOPE_AGENT

__device__ __forceinline__ float ldf_cg(const float* p) { return __hip_atomic_load(p, AS_RLX, SC_AGT); }
__device__ __forceinline__ void stf_cg(float* p, float v) { __hip_atomic_store(p, v, AS_RLX, SC_AGT); }
__device__ __forceinline__ void sth_cg(bf16* p, bf16 v) {
    __hip_atomic_store((unsigned short*)p, __builtin_bit_cast(unsigned short, v), AS_RLX, SC_AGT);
}
__device__ __forceinline__ float2 ldf2_cg(const float* p) {
    unsigned long long u = __hip_atomic_load((const unsigned long long*)p, AS_RLX, SC_AGT);
    return __builtin_bit_cast(float2, u);
}
__device__ __forceinline__ bf16x8 ldh8_cg(const bf16* p) {
    const unsigned long long* q = (const unsigned long long*)p;
    unsigned long long a = __hip_atomic_load(q, AS_RLX, SC_AGT);
    unsigned long long b = __hip_atomic_load(q + 1, AS_RLX, SC_AGT);
    union { unsigned long long u[2]; bf16x8 v; } c;
    c.u[0] = a; c.u[1] = b;
    return c.v;
}
// read two context partial rows (stride 1024 floats), sum, convert
__device__ __forceinline__ bf16x8 cvt8sum_cg(const float* p) {
    float2 a0 = ldf2_cg(p), a1 = ldf2_cg(p + 2), a2 = ldf2_cg(p + 4), a3 = ldf2_cg(p + 6);
    float2 b0 = ldf2_cg(p + 1024), b1 = ldf2_cg(p + 1026), b2 = ldf2_cg(p + 1028), b3 = ldf2_cg(p + 1030);
    bf16x8 r = {(bf16)(a0.x + b0.x), (bf16)(a0.y + b0.y), (bf16)(a1.x + b1.x), (bf16)(a1.y + b1.y),
                (bf16)(a2.x + b2.x), (bf16)(a2.y + b2.y), (bf16)(a3.x + b3.x), (bf16)(a3.y + b3.y)};
    return r;
}

// ---------------------------------------------------------------- f32 -> bf16 bulk convert (n % 8 == 0)
__global__ __launch_bounds__(256) void k_conv(const float* __restrict__ src, bf16* __restrict__ dst, int n) {
    int i0 = (blockIdx.x * 256 + threadIdx.x) * 8;
    if (i0 >= n) return;
    *(bf16x8*)(dst + i0) = cvt8(src + i0);
}

// ---------------------------------------------------------------- init: hb_bf16 = (bf16)state, hb_f32 = state
__global__ __launch_bounds__(256) void k_init(const float* __restrict__ state, bf16* __restrict__ hb,
                                              float* __restrict__ hb32) {
    int i0 = (blockIdx.x * 256 + threadIdx.x) * 8;
    *(bf16x8*)(hb + i0) = cvt8(state + i0);
    *(float4*)(hb32 + i0) = *(const float4*)(state + i0);
    *(float4*)(hb32 + i0 + 4) = *(const float4*)(state + i0 + 4);
}

// ---------------------------------------------------------------- keys_c = (value @ Wk^T) * 2log2e  [bf16]
__global__ __launch_bounds__(256) void k_keys(const bf16* __restrict__ val, const bf16* __restrict__ Wk,
                                              bf16* __restrict__ keys_c) {
    const int lane = threadIdx.x & 63, wave = threadIdx.x >> 6;
    const int l16 = lane & 15, q8 = (lane >> 4) * 8;
    const int mblk = blockIdx.x >> 4, nblk = blockIdx.x & 15;
    const int m_base = mblk * 64 + (wave & 1) * 32;
    const int n_base = nblk * 64 + (wave >> 1) * 32;
    const bf16* a0p = val + (size_t)(m_base + l16) * 1024 + q8;
    const bf16* a1p = a0p + 16 * 1024;
    const bf16* b0p = Wk + (size_t)(n_base + l16) * 1024 + q8;
    const bf16* b1p = b0p + 16 * 1024;
    floatx4 acc[2][2] = {};
    for (int k0 = 0; k0 < 1024; k0 += 32) {
        bf16x8 a0 = *(const bf16x8*)(a0p + k0);
        bf16x8 a1 = *(const bf16x8*)(a1p + k0);
        bf16x8 b0 = *(const bf16x8*)(b0p + k0);
        bf16x8 b1 = *(const bf16x8*)(b1p + k0);
        acc[0][0] = MFMA16(a0, b0, acc[0][0]);
        acc[0][1] = MFMA16(a0, b1, acc[0][1]);
        acc[1][0] = MFMA16(a1, b0, acc[1][0]);
        acc[1][1] = MFMA16(a1, b1, acc[1][1]);
    }
    const int mr = (lane >> 4) * 4;
    for (int im = 0; im < 2; im++)
        for (int in = 0; in < 2; in++)
            for (int r = 0; r < 4; r++) {
                int m = m_base + im * 16 + mr + r;
                int n = n_base + in * 16 + l16;
                keys_c[(size_t)m * 1024 + n] = (bf16)(acc[im][in][r] * TWO_LOG2E);
            }
}

// ---------------------------------------------------------------- barrier state reset (graph-replay safe)
// bar[0..1023]: 64 group counters at stride 16; bar[1024]: generation flag.
__global__ void k_reset(unsigned* bar) {
    for (int i = threadIdx.x; i < 1025; i += blockDim.x)
        __hip_atomic_store(&bar[i], 0u, AS_RLX, SC_AGT);
}

// ---------------------------------------------------------------- tree grid barrier: no fences, no L2 impact
// Cross-block data moves only through coherent-point accesses -> no cache invalidation needed,
// just store-ack ordering (s_waitcnt vmcnt(0)) + arrival counting. Watchdog terminates any stall.
__device__ __forceinline__ void gbar(unsigned* bar, unsigned gen) {
    asm volatile("s_waitcnt vmcnt(0)" ::: "memory");
    __syncthreads();
    const int tid = threadIdx.x;
    if (blockIdx.x == 0) {
        if (tid < 64) {
            if (tid == 0)
                __hip_atomic_fetch_add(&bar[0], 1u, AS_RLX, SC_AGT);
            unsigned long long t0 = __builtin_amdgcn_s_memrealtime();
            for (;;) {   // 64 lanes poll the 64 group counters in parallel
                unsigned v = __hip_atomic_load(&bar[tid * 16], AS_RLX, SC_AGT);
                if (__all((int)(v >= gen * 8u))) break;
                if (__builtin_amdgcn_s_memrealtime() - t0 > WDOG_TICKS) break;
                __builtin_amdgcn_s_sleep(2);
            }
            if (tid == 0) __hip_atomic_store(&bar[1024], gen, AS_RLX, SC_AGT);
        }
    } else {
        if (tid == 0) {
            __hip_atomic_fetch_add(&bar[(blockIdx.x >> 3) * 16], 1u, AS_RLX, SC_AGT);
            unsigned long long t0 = __builtin_amdgcn_s_memrealtime();
            while (__hip_atomic_load(&bar[1024], AS_RLX, SC_AGT) < gen) {
                if (__builtin_amdgcn_s_memrealtime() - t0 > WDOG_TICKS) break;
                __builtin_amdgcn_s_sleep(2);
            }
        }
    }
    __syncthreads();
}

// ---------------------------------------------------------------- persistent kernel: 128 steps x 5 phases
// 512 blocks x 256 thr: P1/P2/P5 on blocks 0..255 (GEMV, cs/mt tiles); P3/P4 on all 512.
// __launch_bounds__(256,2): VGPR capped <=256 -> exactly 2 blocks/CU fit -> all 512 co-resident.
__global__ __launch_bounds__(256, 2) void k_persist(
    const float* __restrict__ emb, const float* __restrict__ mask,
    const bf16* __restrict__ value_c, const bf16* __restrict__ keys_c,
    const bf16* __restrict__ Wih, const bf16* __restrict__ Whh,
    const float* __restrict__ bih, const float* __restrict__ bhh,
    const bf16* __restrict__ Wq, const bf16* __restrict__ Wm,
    const float* __restrict__ bm, const float* __restrict__ v_att,
    bf16* hb, float* hb32, bf16* rnn, float* qc,
    float* scores, float* cpart, float* out_f, unsigned* bar) {
    const int bid = blockIdx.x, tid = threadIdx.x;
    const int lane = tid & 63, w = tid >> 6;
    const int l16 = lane & 15, q8 = (lane >> 4) * 8, mr = (lane >> 4) * 4;
    __shared__ __align__(16) float lds[4096];

    // GEMV tile decomposition (blocks 0..255; XCD-swizzled)
    const int mt = (bid >> 3) & 3;
    const int cs = (bid & 7) | (((bid >> 5) & 7) << 3);
    const int b_row = mt * 16 + l16;
    const int jcol = cs * 16 + l16;

    float biasR = 0.f, biasZ = 0.f, biasXN = 0.f, biasHN = 0.f, biasM = 0.f;
    if (bid < 256) {
        biasR = bih[jcol] + bhh[jcol];
        biasZ = bih[1024 + jcol] + bhh[1024 + jcol];
        biasXN = bih[2048 + jcol];
        biasHN = bhh[2048 + jcol];
        biasM = bm[jcol];
    }

    // P3 mapping: 2048 waves -> (b, 16-row chunk)
    const int gw = bid * 4 + w;
    const int p3_b = gw >> 5;
    const int p3_n0 = (gw & 31) * 16;

    // P4 mapping: 512 blocks = (b 64) x (hc 4) x (nh 2)
    const int b4 = bid >> 3, hc = (bid >> 1) & 3, nh = bid & 1;

    // v_att resident in registers all 128 steps
    float vv[16];
    {
        float4 a0 = *(const float4*)(v_att + lane * 8);
        float4 a1 = *(const float4*)(v_att + lane * 8 + 4);
        float4 b0 = *(const float4*)(v_att + 512 + lane * 8);
        float4 b1 = *(const float4*)(v_att + 512 + lane * 8 + 4);
        vv[0] = a0.x; vv[1] = a0.y; vv[2] = a0.z; vv[3] = a0.w;
        vv[4] = a1.x; vv[5] = a1.y; vv[6] = a1.z; vv[7] = a1.w;
        vv[8] = b0.x; vv[9] = b0.y; vv[10] = b0.z; vv[11] = b0.w;
        vv[12] = b1.x; vv[13] = b1.y; vv[14] = b1.z; vv[15] = b1.w;
    }

    unsigned gen = 0;
    for (int step = 0; step < Ld; ++step) {
        // ================= P1: GRU gates -> rnn (blocks 0..255, 4-way K-split) =================
        if (bid < 256) {
            floatx4 aR = {}, aZ = {}, aXN = {}, aHN = {};
            {   // seg1: emb (cached loads), K=512, wave slice 128
                const float* ae = emb + ((size_t)b_row * Ld + step) * Ed + w * 128 + q8;
                const bf16* w0 = Wih + (size_t)jcol * 1536 + w * 128 + q8;
                const bf16* w1 = Wih + (size_t)(1024 + jcol) * 1536 + w * 128 + q8;
                const bf16* w2 = Wih + (size_t)(2048 + jcol) * 1536 + w * 128 + q8;
#pragma unroll
                for (int k = 0; k < 128; k += 32) {
                    bf16x8 a = cvt8(ae + k);
                    aR = MFMA16(a, *(const bf16x8*)(w0 + k), aR);
                    aZ = MFMA16(a, *(const bf16x8*)(w1 + k), aZ);
                    aXN = MFMA16(a, *(const bf16x8*)(w2 + k), aXN);
                }
            }
            {   // seg2: hb (coherent loads), K=1024, wave slice 256
                const bf16* ah = hb + (size_t)b_row * Hd + w * 256 + q8;
                const bf16* u0 = Wih + (size_t)jcol * 1536 + 512 + w * 256 + q8;
                const bf16* u1 = Wih + (size_t)(1024 + jcol) * 1536 + 512 + w * 256 + q8;
                const bf16* u2 = Wih + (size_t)(2048 + jcol) * 1536 + 512 + w * 256 + q8;
                const bf16* v0 = Whh + (size_t)jcol * 1024 + w * 256 + q8;
                const bf16* v1 = Whh + (size_t)(1024 + jcol) * 1024 + w * 256 + q8;
                const bf16* v2 = Whh + (size_t)(2048 + jcol) * 1024 + w * 256 + q8;
#pragma unroll 4
                for (int k = 0; k < 256; k += 32) {
                    bf16x8 a = ldh8_cg(ah + k);
                    aR = MFMA16(a, *(const bf16x8*)(u0 + k), aR);
                    aZ = MFMA16(a, *(const bf16x8*)(u1 + k), aZ);
                    aXN = MFMA16(a, *(const bf16x8*)(u2 + k), aXN);
                    aHN = MFMA16(a, *(const bf16x8*)(v2 + k), aHN);
                    aR = MFMA16(a, *(const bf16x8*)(v0 + k), aR);
                    aZ = MFMA16(a, *(const bf16x8*)(v1 + k), aZ);
                }
            }
            *(floatx4*)&lds[w * 1024 + 0 + lane * 4] = aR;
            *(floatx4*)&lds[w * 1024 + 256 + lane * 4] = aZ;
            *(floatx4*)&lds[w * 1024 + 512 + lane * 4] = aXN;
            *(floatx4*)&lds[w * 1024 + 768 + lane * 4] = aHN;
            __syncthreads();
            if (tid < 64) {
                floatx4 R = {}, Z = {}, XN = {}, HN = {};
#pragma unroll
                for (int ww = 0; ww < 4; ++ww) {
                    R += *(floatx4*)&lds[ww * 1024 + 0 + lane * 4];
                    Z += *(floatx4*)&lds[ww * 1024 + 256 + lane * 4];
                    XN += *(floatx4*)&lds[ww * 1024 + 512 + lane * 4];
                    HN += *(floatx4*)&lds[ww * 1024 + 768 + lane * 4];
                }
#pragma unroll
                for (int r = 0; r < 4; ++r) {
                    int b = mt * 16 + mr + r;
                    float rg = sigmoid_f(R[r] + biasR);
                    float zg = sigmoid_f(Z[r] + biasZ);
                    float ng = tanh_f(XN[r] + biasXN + rg * (HN[r] + biasHN));
                    float hp = ldf_cg(&hb32[(size_t)b * Hd + jcol]);
                    sth_cg(&rnn[(size_t)b * Hd + jcol], (bf16)((1.0f - zg) * ng + zg * hp));
                }
            }
        }
        gbar(bar, ++gen);

        // ================= P2: q = (rnn @ Wq^T) * 2log2e (blocks 0..255) =================
        if (bid < 256) {
            const bf16* ap = rnn + (size_t)b_row * Hd + w * 256 + q8;
            const bf16* bp = Wq + (size_t)jcol * Hd + w * 256 + q8;
            floatx4 acc = {};
#pragma unroll 4
            for (int k = 0; k < 256; k += 32)
                acc = MFMA16(ldh8_cg(ap + k), *(const bf16x8*)(bp + k), acc);
            *(floatx4*)&lds[w * 256 + lane * 4] = acc;
            __syncthreads();
            if (tid < 64) {
                floatx4 s = *(floatx4*)&lds[lane * 4] + *(floatx4*)&lds[256 + lane * 4] +
                            *(floatx4*)&lds[512 + lane * 4] + *(floatx4*)&lds[768 + lane * 4];
#pragma unroll
                for (int r = 0; r < 4; ++r)
                    stf_cg(&qc[(size_t)(mt * 16 + mr + r) * Hd + jcol], s[r] * TWO_LOG2E);
            }
        }
        gbar(bar, ++gen);

        // ================= P3: scores[b,n] = sum_h v * tanh(q + k)  (all 512 blocks) =================
        {
            const float* qp = qc + (size_t)p3_b * Hd;
            float qv[16];
            {
                float2 a0 = ldf2_cg(qp + lane * 8), a1 = ldf2_cg(qp + lane * 8 + 2);
                float2 a2 = ldf2_cg(qp + lane * 8 + 4), a3 = ldf2_cg(qp + lane * 8 + 6);
                float2 b0 = ldf2_cg(qp + 512 + lane * 8), b1 = ldf2_cg(qp + 512 + lane * 8 + 2);
                float2 b2 = ldf2_cg(qp + 512 + lane * 8 + 4), b3 = ldf2_cg(qp + 512 + lane * 8 + 6);
                qv[0] = a0.x; qv[1] = a0.y; qv[2] = a1.x; qv[3] = a1.y;
                qv[4] = a2.x; qv[5] = a2.y; qv[6] = a3.x; qv[7] = a3.y;
                qv[8] = b0.x; qv[9] = b0.y; qv[10] = b1.x; qv[11] = b1.y;
                qv[12] = b2.x; qv[13] = b2.y; qv[14] = b3.x; qv[15] = b3.y;
            }
            const bf16* kbase = keys_c + ((size_t)p3_b * Nd + p3_n0) * Hd + lane * 8;
#pragma unroll 2
            for (int i = 0; i < 16; ++i) {
                const bf16* kp = kbase + (size_t)i * Hd;
                bf16x8 k0 = *(const bf16x8*)kp;
                bf16x8 k1 = *(const bf16x8*)(kp + 512);
                float acc = 0.f;
#pragma unroll
                for (int jj = 0; jj < 8; ++jj) {
                    float x = qv[jj] + (float)k0[jj];
                    float tv = __builtin_fmaf(-2.0f, frcp(fexp2(x) + 1.0f), 1.0f);
                    acc = __builtin_fmaf(vv[jj], tv, acc);
                }
#pragma unroll
                for (int jj = 0; jj < 8; ++jj) {
                    float x = qv[8 + jj] + (float)k1[jj];
                    float tv = __builtin_fmaf(-2.0f, frcp(fexp2(x) + 1.0f), 1.0f);
                    acc = __builtin_fmaf(vv[8 + jj], tv, acc);
                }
#pragma unroll
                for (int off = 32; off; off >>= 1) acc += __shfl_down(acc, off, 64);
                if (lane == 0) stf_cg(&scores[(size_t)p3_b * Nd + p3_n0 + i], acc);
            }
        }
        gbar(bar, ++gen);

        // ================= P4: softmax + context partials (all 512 blocks) =================
        {
            float* sm = lds;           // [512]
            float* red = lds + 512;    // [8]
            float* part = lds + 768;   // [1024]
            float s0 = ldf_cg(&scores[(size_t)b4 * Nd + tid]);
            float s1 = ldf_cg(&scores[(size_t)b4 * Nd + 256 + tid]);
            if (!(mask[(size_t)b4 * Nd + tid] > 0.f)) s0 = -1e9f;
            if (!(mask[(size_t)b4 * Nd + 256 + tid] > 0.f)) s1 = -1e9f;
            float m = fmaxf(s0, s1);
#pragma unroll
            for (int off = 32; off; off >>= 1) m = fmaxf(m, __shfl_xor(m, off, 64));
            if (lane == 0) red[w] = m;
            __syncthreads();
            float mx = fmaxf(fmaxf(red[0], red[1]), fmaxf(red[2], red[3]));
            float p0 = fexp2((s0 - mx) * LOG2E);
            float p1 = fexp2((s1 - mx) * LOG2E);
            float ss = p0 + p1;
#pragma unroll
            for (int off = 32; off; off >>= 1) ss += __shfl_xor(ss, off, 64);
            if (lane == 0) red[4 + w] = ss;
            __syncthreads();
            float inv = frcp(red[4] + red[5] + red[6] + red[7]);
            sm[tid] = p0 * inv;
            sm[256 + tid] = p1 * inv;
            __syncthreads();
            if (hc == 0 && nh == 0) {   // attns output: plain stores (host-read after kernel end)
                float* ao = out_f + (size_t)Bd * Ld * Hd + ((size_t)b4 * Ld + step) * Nd;
                ao[tid] = sm[tid];
                ao[256 + tid] = sm[256 + tid];
            }
            // ctx partial: block covers n in [nh*256, nh*256+256), h in [hc*256, hc*256+256)
            const int h0 = hc * 256 + lane * 4;
            const bf16* vb = value_c + ((size_t)b4 * Nd + nh * 256 + w * 64) * Hd + h0;
            float c0 = 0.f, c1 = 0.f, c2 = 0.f, c3 = 0.f;
#pragma unroll 4
            for (int n = 0; n < 64; ++n) {
                float a = sm[nh * 256 + w * 64 + n];
                bf16x4 vt = *(const bf16x4*)(vb + (size_t)n * Hd);
                c0 = __builtin_fmaf(a, (float)vt[0], c0);
                c1 = __builtin_fmaf(a, (float)vt[1], c1);
                c2 = __builtin_fmaf(a, (float)vt[2], c2);
                c3 = __builtin_fmaf(a, (float)vt[3], c3);
            }
            *(floatx4*)&part[w * 256 + lane * 4] = (floatx4){c0, c1, c2, c3};
            __syncthreads();
            stf_cg(&cpart[((size_t)b4 * 2 + nh) * 1024 + hc * 256 + tid],
                   part[tid] + part[256 + tid] + part[512 + tid] + part[768 + tid]);
        }
        gbar(bar, ++gen);

        // ================= P5: new_state = tanh([rnn|ctx] @ Wm^T + bm) (blocks 0..255) =================
        if (bid < 256) {
            const bf16* Bp = Wm + (size_t)jcol * 2048 + q8;
            floatx4 acc = {};
            if (w < 2) {
                const bf16* ar = rnn + (size_t)b_row * Hd + w * 512 + q8;
                const bf16* bp = Bp + w * 512;
#pragma unroll 4
                for (int k = 0; k < 512; k += 32)
                    acc = MFMA16(ldh8_cg(ar + k), *(const bf16x8*)(bp + k), acc);
            } else {
                const float* ac = cpart + (size_t)b_row * 2 * 1024 + (w - 2) * 512 + q8;
                const bf16* bp = Bp + 1024 + (w - 2) * 512;
#pragma unroll 4
                for (int k = 0; k < 512; k += 32)
                    acc = MFMA16(cvt8sum_cg(ac + k), *(const bf16x8*)(bp + k), acc);
            }
            *(floatx4*)&lds[w * 256 + lane * 4] = acc;
            __syncthreads();
            if (tid < 64) {
                floatx4 s = *(floatx4*)&lds[lane * 4] + *(floatx4*)&lds[256 + lane * 4] +
                            *(floatx4*)&lds[512 + lane * 4] + *(floatx4*)&lds[768 + lane * 4];
#pragma unroll
                for (int r = 0; r < 4; ++r) {
                    int b = mt * 16 + mr + r;
                    float h = tanh_f(s[r] + biasM);
                    out_f[((size_t)b * Ld + step) * Hd + jcol] = h;   // host-read: plain store
                    sth_cg(&hb[(size_t)b * Hd + jcol], (bf16)h);
                    stf_cg(&hb32[(size_t)b * Hd + jcol], h);
                }
            }
        }
        gbar(bar, ++gen);
    }
}

extern "C" void kernel_launch(void* const* d_in, const int* in_sizes, int n_in,
                              void* d_out, int out_size, void* d_ws, size_t ws_size,
                              hipStream_t stream) {
    const float* emb = (const float*)d_in[0];
    const float* value = (const float*)d_in[1];
    const float* mask = (const float*)d_in[2];
    const float* state = (const float*)d_in[3];
    const float* Wih = (const float*)d_in[4];
    const float* bih = (const float*)d_in[5];
    const float* Whh = (const float*)d_in[6];
    const float* bhh = (const float*)d_in[7];
    const float* Wq = (const float*)d_in[8];
    const float* Wk = (const float*)d_in[9];
    const float* v_att = (const float*)d_in[10];
    const float* Wm = (const float*)d_in[11];
    const float* bm = (const float*)d_in[12];

    // ws layout (bytes); total = 159,780,880 (< ~167 MB available)
    char* ws = (char*)d_ws;
    bf16* hb = (bf16*)(ws);                   //     131,072
    float* hb32 = (float*)(ws + 131072);      //     262,144
    bf16* rnn = (bf16*)(ws + 393216);         //     131,072
    float* qc = (float*)(ws + 524288);        //     262,144
    float* scores = (float*)(ws + 786432);    //     131,072
    float* cpart = (float*)(ws + 917504);     //     524,288  [64][2][1024] f32 ctx partials
    bf16* value_c = (bf16*)(ws + 1441792);    //  67,108,864
    bf16* Wih_c = (bf16*)(ws + 68550656);     //   9,437,184
    bf16* Whh_c = (bf16*)(ws + 77987840);     //   6,291,456
    bf16* Wq_c = (bf16*)(ws + 84279296);      //   2,097,152
    bf16* Wk_c = (bf16*)(ws + 86376448);      //   2,097,152
    bf16* Wm_c = (bf16*)(ws + 88473600);      //   4,194,304
    bf16* keys_c = (bf16*)(ws + 92667904);    //  67,108,864
    unsigned* bar = (unsigned*)(ws + 159776768);  // 1025 uints: 64 padded counters + flag

    float* out_f = (float*)d_out;

    k_conv<<<16384, 256, 0, stream>>>(value, value_c, 33554432);
    k_conv<<<2304, 256, 0, stream>>>(Wih, Wih_c, 4718592);
    k_conv<<<1536, 256, 0, stream>>>(Whh, Whh_c, 3145728);
    k_conv<<<512, 256, 0, stream>>>(Wq, Wq_c, 1048576);
    k_conv<<<512, 256, 0, stream>>>(Wk, Wk_c, 1048576);
    k_conv<<<1024, 256, 0, stream>>>(Wm, Wm_c, 2097152);
    k_init<<<32, 256, 0, stream>>>(state, hb, hb32);
    k_keys<<<8192, 256, 0, stream>>>(value_c, Wk_c, keys_c);
    k_reset<<<1, 256, 0, stream>>>(bar);

    k_persist<<<NBLK, 256, 0, stream>>>(emb, mask, value_c, keys_c, Wih_c, Whh_c, bih, bhh,
                                        Wq_c, Wm_c, bm, v_att, hb, hb32, rnn, qc,
                                        scores, cpart, out_f, bar);
}